// Round 2
// baseline (1478.572 us; speedup 1.0000x reference)
//
#include <hip/hip_runtime.h>

// GCN 2-layer forward, f32.
// Layer: out[i] = act( dinv[i] * ( sum_{e: dst=i} h'[src_e] + h'[i] ) + b )
// where h' = (x @ W) * dinv[row]  (dinv[src] folded into GEMM epilogue,
// dinv[dst] + self-loop folded into the epilogue kernel).

__global__ __launch_bounds__(256) void deg_kernel(const int* __restrict__ dst,
                                                  float* __restrict__ deg, int E) {
    int i = blockIdx.x * 256 + threadIdx.x;
    if (i < E) atomicAdd(&deg[dst[i]], 1.0f);
}

__global__ __launch_bounds__(256) void dinv_kernel(float* __restrict__ deg, int n) {
    int i = blockIdx.x * 256 + threadIdx.x;
    if (i < n) deg[i] = rsqrtf(deg[i] + 1.0f);  // +1 = self loop; always > 0
}

// H[row, f] = dinv[row] * sum_k X[row,k] * W[k,f]
template <int K, int F>
__global__ __launch_bounds__(256) void gemm_scale(const float* __restrict__ X,
                                                  const float* __restrict__ W,
                                                  const float* __restrict__ dinv,
                                                  float* __restrict__ H, int n) {
    __shared__ float sW[K * F];
    __shared__ float sX[16 * K];
    const int tid = threadIdx.x;
    for (int i = tid; i < K * F; i += 256) sW[i] = W[i];
    const int row0 = blockIdx.x * 16;
    for (int i = tid; i < 16 * K; i += 256) {
        int r = row0 + i / K;
        sX[i] = (r < n) ? X[(size_t)r * K + (i % K)] : 0.0f;
    }
    __syncthreads();
    for (int i = tid; i < 16 * F; i += 256) {
        int r = i / F, f = i % F;
        int row = row0 + r;
        if (row >= n) continue;
        float acc = 0.0f;
#pragma unroll
        for (int k = 0; k < K; ++k) acc += sX[r * K + k] * sW[k * F + f];
        H[(size_t)row * F + f] = acc * dinv[row];
    }
}

// One thread per (edge, float4-chunk): agg[dst] += h'[src]
template <int F>
__global__ __launch_bounds__(256) void scatter_kernel(const float* __restrict__ H,
                                                      const int* __restrict__ src,
                                                      const int* __restrict__ dst,
                                                      float* __restrict__ agg,
                                                      long long total) {
    constexpr int Q = F / 4;  // float4 chunks per edge
    long long i = (long long)blockIdx.x * 256 + threadIdx.x;
    if (i >= total) return;
    int e = (int)(i / Q);
    int q = (int)(i % Q);
    int s = src[e];
    int d = dst[e];
    float4 v = ((const float4*)(H + (size_t)s * F))[q];
    float* p = agg + (size_t)d * F + q * 4;
    atomicAdd(p + 0, v.x);
    atomicAdd(p + 1, v.y);
    atomicAdd(p + 2, v.z);
    atomicAdd(p + 3, v.w);
}

// out[i,f] = act( (agg[i,f] + h'[i,f]) * dinv[i] + b[f] )   (in-place safe: agg==out)
template <int F, bool RELU>
__global__ __launch_bounds__(256) void epilogue_kernel(const float* __restrict__ agg,
                                                       const float* __restrict__ Hp,
                                                       const float* __restrict__ dinv,
                                                       const float* __restrict__ b,
                                                       float* __restrict__ out, int n) {
    int i = blockIdx.x * 256 + threadIdx.x;
    if (i >= n * F) return;
    int node = i / F, f = i % F;
    float v = (agg[i] + Hp[i]) * dinv[node] + b[f];
    if (RELU) v = fmaxf(v, 0.0f);
    out[i] = v;
}

extern "C" void kernel_launch(void* const* d_in, const int* in_sizes, int n_in,
                              void* d_out, int out_size, void* d_ws, size_t ws_size,
                              hipStream_t stream) {
    const float* x   = (const float*)d_in[0];
    const int*  eidx = (const int*)d_in[1];
    const float* W1  = (const float*)d_in[2];
    const float* b1  = (const float*)d_in[3];
    const float* W2  = (const float*)d_in[4];
    const float* b2  = (const float*)d_in[5];

    const int IN = 96, HID = 96, OUT = 32;
    const int N = in_sizes[0] / IN;   // 50000
    const int E = in_sizes[1] / 2;    // 800000
    const int* src = eidx;
    const int* dst = eidx + E;

    float* out  = (float*)d_out;
    float* x1   = out;                       // [N, 96]
    float* out2 = out + (size_t)N * HID;     // [N, 32]

    char* ws = (char*)d_ws;
    float* dinv = (float*)ws;                                            // N floats
    float* hp   = (float*)(ws + (((size_t)N * 4 + 511) / 512) * 512);    // N*96 floats

    // Zero accumulators (d_out is poisoned 0xAA; atomics accumulate into it).
    hipMemsetAsync(d_out, 0, (size_t)out_size * sizeof(float), stream);
    hipMemsetAsync(dinv, 0, (size_t)N * sizeof(float), stream);

    deg_kernel<<<(E + 255) / 256, 256, 0, stream>>>(dst, dinv, E);
    dinv_kernel<<<(N + 255) / 256, 256, 0, stream>>>(dinv, N);

    // Layer 1
    gemm_scale<96, 96><<<(N + 15) / 16, 256, 0, stream>>>(x, W1, dinv, hp, N);
    {
        long long tot = (long long)E * (HID / 4);
        scatter_kernel<96><<<(int)((tot + 255) / 256), 256, 0, stream>>>(hp, src, dst, x1, tot);
    }
    epilogue_kernel<96, true><<<(N * HID + 255) / 256, 256, 0, stream>>>(x1, hp, dinv, b1, x1, N);

    // Layer 2 (reads x1 from d_out; reuses hp region for h2')
    gemm_scale<96, 32><<<(N + 15) / 16, 256, 0, stream>>>(x1, W2, dinv, hp, N);
    {
        long long tot = (long long)E * (OUT / 4);
        scatter_kernel<32><<<(int)((tot + 255) / 256), 256, 0, stream>>>(hp, src, dst, out2, tot);
    }
    epilogue_kernel<32, false><<<(N * OUT + 255) / 256, 256, 0, stream>>>(out2, hp, dinv, b2, out2, N);
}

// Round 3
// 337.946 us; speedup vs baseline: 4.3752x; 4.3752x over previous
//
#include <hip/hip_runtime.h>

// GCN 2-layer forward, f32 — atomic-free gather formulation.
// h' = (x @ W) * dinv[row]
// out[i] = act( dinv[i] * ( sum_{e: dst=i} h'[src_e] + h'[i] ) + b )
// Edges are bucketed into a dst-CSR once; both layers reuse it.

// ---------- degree / dinv ----------
__global__ __launch_bounds__(256) void deg_int_kernel(const int* __restrict__ dst,
                                                      int* __restrict__ deg, int E) {
    int i = blockIdx.x * 256 + threadIdx.x;
    if (i < E) atomicAdd(&deg[dst[i]], 1);
}

__global__ __launch_bounds__(256) void dinv_kernel(const int* __restrict__ deg,
                                                   float* __restrict__ dinv, int n) {
    int i = blockIdx.x * 256 + threadIdx.x;
    if (i < n) dinv[i] = rsqrtf((float)deg[i] + 1.0f);  // +1 = self loop
}

// ---------- prefix sum (1024 elems / block) ----------
__global__ __launch_bounds__(256) void scan1(const int* __restrict__ deg,
                                             int* __restrict__ rp1,  // row_ptr + 1
                                             int* __restrict__ bsum, int n) {
    __shared__ int s[256];
    const int tid = threadIdx.x;
    const int base = blockIdx.x * 1024 + tid * 4;
    int v0 = (base + 0 < n) ? deg[base + 0] : 0;
    int v1 = (base + 1 < n) ? deg[base + 1] : 0;
    int v2 = (base + 2 < n) ? deg[base + 2] : 0;
    int v3 = (base + 3 < n) ? deg[base + 3] : 0;
    int sum = v0 + v1 + v2 + v3;
    s[tid] = sum;
    __syncthreads();
    for (int off = 1; off < 256; off <<= 1) {
        int t = (tid >= off) ? s[tid - off] : 0;
        __syncthreads();
        s[tid] += t;
        __syncthreads();
    }
    int run = s[tid] - sum;  // exclusive prefix of this thread's chunk
    run += v0; if (base + 0 < n) rp1[base + 0] = run;
    run += v1; if (base + 1 < n) rp1[base + 1] = run;
    run += v2; if (base + 2 < n) rp1[base + 2] = run;
    run += v3; if (base + 3 < n) rp1[base + 3] = run;
    if (tid == 255) bsum[blockIdx.x] = s[255];
}

__global__ void scan2(int* __restrict__ bsum, int nb) {
    if (threadIdx.x == 0 && blockIdx.x == 0) {
        int acc = 0;
        for (int i = 0; i < nb; ++i) { int t = bsum[i]; bsum[i] = acc; acc += t; }
    }
}

__global__ __launch_bounds__(256) void scan3(int* __restrict__ row_ptr,
                                             const int* __restrict__ bsum, int n) {
    int i = blockIdx.x * 256 + threadIdx.x;
    if (i < n) row_ptr[i + 1] += bsum[i >> 10];
    if (i == 0) row_ptr[0] = 0;
}

// ---------- CSR fill ----------
__global__ __launch_bounds__(256) void fill_kernel(const int* __restrict__ src,
                                                   const int* __restrict__ dst,
                                                   const int* __restrict__ row_ptr,
                                                   int* __restrict__ cursor,
                                                   int* __restrict__ esrc, int E) {
    int e = blockIdx.x * 256 + threadIdx.x;
    if (e >= E) return;
    int d = dst[e];
    int pos = row_ptr[d] + atomicAdd(&cursor[d], 1);
    esrc[pos] = src[e];
}

// ---------- GEMM: H[row,f] = dinv[row] * sum_k X[row,k] * W[k,f] ----------
template <int K, int F>
__global__ __launch_bounds__(256) void gemm_scale(const float* __restrict__ X,
                                                  const float* __restrict__ W,
                                                  const float* __restrict__ dinv,
                                                  float* __restrict__ H, int n) {
    __shared__ float sW[K * F];
    __shared__ float sX[16 * K];
    const int tid = threadIdx.x;
    for (int i = tid; i < K * F; i += 256) sW[i] = W[i];
    const int row0 = blockIdx.x * 16;
    for (int i = tid; i < 16 * K; i += 256) {
        int r = row0 + i / K;
        sX[i] = (r < n) ? X[(size_t)r * K + (i % K)] : 0.0f;
    }
    __syncthreads();
    for (int i = tid; i < 16 * F; i += 256) {
        int r = i / F, f = i % F;
        int row = row0 + r;
        if (row >= n) continue;
        float acc = 0.0f;
#pragma unroll
        for (int k = 0; k < K; ++k) acc += sX[r * K + k] * sW[k * F + f];
        H[(size_t)row * F + f] = acc * dinv[row];
    }
}

// ---------- gather-aggregate + epilogue (F threads per node) ----------
template <int F, int BS, bool RELU>
__global__ __launch_bounds__(BS) void agg_kernel(const float* __restrict__ H,
                                                 const int* __restrict__ row_ptr,
                                                 const int* __restrict__ esrc,
                                                 const float* __restrict__ dinv,
                                                 const float* __restrict__ b,
                                                 float* __restrict__ out, int n) {
    const int tid = threadIdx.x;
    const int node = blockIdx.x * (BS / F) + tid / F;
    const int f = tid % F;
    if (node >= n) return;
    float acc = H[(size_t)node * F + f];  // self loop
    const int beg = row_ptr[node], end = row_ptr[node + 1];
    for (int e = beg; e < end; ++e) {
        int s = esrc[e];
        acc += H[(size_t)s * F + f];
    }
    float v = acc * dinv[node] + b[f];
    if (RELU) v = fmaxf(v, 0.0f);
    out[(size_t)node * F + f] = v;
}

extern "C" void kernel_launch(void* const* d_in, const int* in_sizes, int n_in,
                              void* d_out, int out_size, void* d_ws, size_t ws_size,
                              hipStream_t stream) {
    const float* x   = (const float*)d_in[0];
    const int*  eidx = (const int*)d_in[1];
    const float* W1  = (const float*)d_in[2];
    const float* b1  = (const float*)d_in[3];
    const float* W2  = (const float*)d_in[4];
    const float* b2  = (const float*)d_in[5];

    const int IN = 96, HID = 96, OUT = 32;
    const int N = in_sizes[0] / IN;   // 50000
    const int E = in_sizes[1] / 2;    // 800000
    const int* src = eidx;
    const int* dst = eidx + E;

    float* out  = (float*)d_out;
    float* x1   = out;                       // [N, 96]
    float* out2 = out + (size_t)N * HID;     // [N, 32]

    auto align512 = [](size_t x) { return ((x + 511) / 512) * 512; };
    char* ws = (char*)d_ws;
    size_t off = 0;
    float* dinv   = (float*)(ws + off); off += align512((size_t)N * 4);
    int* deg      = (int*)(ws + off);   off += align512((size_t)N * 4);   // later reused as cursor
    int* row_ptr  = (int*)(ws + off);   off += align512((size_t)(N + 1) * 4);
    int* bsum     = (int*)(ws + off);   off += align512(64 * 4);
    int* esrc     = (int*)(ws + off);   off += align512((size_t)E * 4);
    float* hp     = (float*)(ws + off); off += align512((size_t)N * 96 * 4);

    const int nb = (N + 1023) / 1024;  // scan blocks

    // ---- CSR build (once, reused by both layers) ----
    hipMemsetAsync(deg, 0, (size_t)N * sizeof(int), stream);
    deg_int_kernel<<<(E + 255) / 256, 256, 0, stream>>>(dst, deg, E);
    dinv_kernel<<<(N + 255) / 256, 256, 0, stream>>>(deg, dinv, N);
    scan1<<<nb, 256, 0, stream>>>(deg, row_ptr + 1, bsum, N);
    hipMemsetAsync(deg, 0, (size_t)N * sizeof(int), stream);  // reuse as cursor
    scan2<<<1, 64, 0, stream>>>(bsum, nb);
    scan3<<<(N + 255) / 256, 256, 0, stream>>>(row_ptr, bsum, N);
    fill_kernel<<<(E + 255) / 256, 256, 0, stream>>>(src, dst, row_ptr, deg, esrc, E);

    // ---- Layer 1 ----
    gemm_scale<96, 96><<<(N + 15) / 16, 256, 0, stream>>>(x, W1, dinv, hp, N);
    agg_kernel<96, 192, true><<<(N + 1) / 2, 192, 0, stream>>>(hp, row_ptr, esrc, dinv, b1, x1, N);

    // ---- Layer 2 ----
    gemm_scale<96, 32><<<(N + 15) / 16, 256, 0, stream>>>(x1, W2, dinv, hp, N);
    agg_kernel<32, 256, false><<<(N + 7) / 8, 256, 0, stream>>>(hp, row_ptr, esrc, dinv, b2, out2, N);
}

// Round 4
// 204.858 us; speedup vs baseline: 7.2175x; 1.6497x over previous
//
#include <hip/hip_runtime.h>

// GCN 2-layer forward, f32 — atomic-free gather formulation, MLP-optimized.
// h' = (x @ W) * dinv[row]
// out[i] = act( dinv[i] * ( sum_{e: dst=i} h'[src_e] + h'[i] ) + b )

// ---------- degree / dinv ----------
__global__ __launch_bounds__(256) void deg_int_kernel(const int* __restrict__ dst,
                                                      int* __restrict__ deg, int E) {
    int i = blockIdx.x * 256 + threadIdx.x;
    if (i < E) atomicAdd(&deg[dst[i]], 1);
}

__global__ __launch_bounds__(256) void dinv_kernel(const int* __restrict__ deg,
                                                   float* __restrict__ dinv, int n) {
    int i = blockIdx.x * 256 + threadIdx.x;
    if (i < n) dinv[i] = rsqrtf((float)deg[i] + 1.0f);  // +1 = self loop
}

// ---------- prefix sum (1024 elems / block) ----------
__global__ __launch_bounds__(256) void scan1(const int* __restrict__ deg,
                                             int* __restrict__ rp1,  // row_ptr + 1
                                             int* __restrict__ bsum, int n) {
    __shared__ int s[256];
    const int tid = threadIdx.x;
    const int base = blockIdx.x * 1024 + tid * 4;
    int v0 = (base + 0 < n) ? deg[base + 0] : 0;
    int v1 = (base + 1 < n) ? deg[base + 1] : 0;
    int v2 = (base + 2 < n) ? deg[base + 2] : 0;
    int v3 = (base + 3 < n) ? deg[base + 3] : 0;
    int sum = v0 + v1 + v2 + v3;
    s[tid] = sum;
    __syncthreads();
    for (int off = 1; off < 256; off <<= 1) {
        int t = (tid >= off) ? s[tid - off] : 0;
        __syncthreads();
        s[tid] += t;
        __syncthreads();
    }
    int run = s[tid] - sum;
    run += v0; if (base + 0 < n) rp1[base + 0] = run;
    run += v1; if (base + 1 < n) rp1[base + 1] = run;
    run += v2; if (base + 2 < n) rp1[base + 2] = run;
    run += v3; if (base + 3 < n) rp1[base + 3] = run;
    if (tid == 255) bsum[blockIdx.x] = s[255];
}

__global__ void scan2(int* __restrict__ bsum, int nb) {
    if (threadIdx.x == 0 && blockIdx.x == 0) {
        int acc = 0;
        for (int i = 0; i < nb; ++i) { int t = bsum[i]; bsum[i] = acc; acc += t; }
    }
}

__global__ __launch_bounds__(256) void scan3(int* __restrict__ row_ptr,
                                             const int* __restrict__ bsum, int n) {
    int i = blockIdx.x * 256 + threadIdx.x;
    if (i < n) row_ptr[i + 1] += bsum[i >> 10];
    if (i == 0) row_ptr[0] = 0;
}

// ---------- CSR fill ----------
__global__ __launch_bounds__(256) void fill_kernel(const int* __restrict__ src,
                                                   const int* __restrict__ dst,
                                                   const int* __restrict__ row_ptr,
                                                   int* __restrict__ cursor,
                                                   int* __restrict__ esrc, int E) {
    int e = blockIdx.x * 256 + threadIdx.x;
    if (e >= E) return;
    int d = dst[e];
    int pos = row_ptr[d] + atomicAdd(&cursor[d], 1);
    esrc[pos] = src[e];
}

// ---------- GEMM: H[row,f] = dinv[row] * sum_k X[row,k] * W[k,f] ----------
// Register-tiled: each thread computes 2 rows x 8 cols.
template <int F, int ROWS, int NT>
__global__ __launch_bounds__(NT) void gemm_tile(const float* __restrict__ X,
                                                const float* __restrict__ W,
                                                const float* __restrict__ dinv,
                                                float* __restrict__ H, int n) {
    constexpr int K = 96;
    constexpr int CQ2 = F / 8;  // col-octets per row
    __shared__ float sX[ROWS * K];
    __shared__ float sW[K * F];
    const int tid = threadIdx.x;
    const int row0 = blockIdx.x * ROWS;

    // stage W (float4, coalesced)
    {
        const float4* Wv = (const float4*)W;
        float4* sWv = (float4*)sW;
        for (int i = tid; i < K * F / 4; i += NT) sWv[i] = Wv[i];
    }
    // stage X tile
    if (row0 + ROWS <= n) {
        const float4* Xv = (const float4*)(X + (size_t)row0 * K);
        float4* sXv = (float4*)sX;
        for (int i = tid; i < ROWS * K / 4; i += NT) sXv[i] = Xv[i];
    } else {
        for (int i = tid; i < ROWS * K; i += NT) {
            int r = row0 + i / K;
            sX[i] = (r < n) ? X[(size_t)r * K + (i % K)] : 0.0f;
        }
    }
    __syncthreads();

    const int rp = tid / CQ2;       // 0 .. ROWS/2-1
    const int c = tid % CQ2;        // 0 .. CQ2-1
    const int r0 = rp * 2;
    float4 a00 = {0, 0, 0, 0}, a01 = {0, 0, 0, 0};
    float4 a10 = {0, 0, 0, 0}, a11 = {0, 0, 0, 0};
    const float4* sWv = (const float4*)sW;
#pragma unroll 4
    for (int k = 0; k < K; ++k) {
        float x0 = sX[r0 * K + k];
        float x1 = sX[(r0 + 1) * K + k];
        float4 w0 = sWv[k * (F / 4) + c * 2];
        float4 w1 = sWv[k * (F / 4) + c * 2 + 1];
        a00.x += x0 * w0.x; a00.y += x0 * w0.y; a00.z += x0 * w0.z; a00.w += x0 * w0.w;
        a01.x += x0 * w1.x; a01.y += x0 * w1.y; a01.z += x0 * w1.z; a01.w += x0 * w1.w;
        a10.x += x1 * w0.x; a10.y += x1 * w0.y; a10.z += x1 * w0.z; a10.w += x1 * w0.w;
        a11.x += x1 * w1.x; a11.y += x1 * w1.y; a11.z += x1 * w1.z; a11.w += x1 * w1.w;
    }
    int ra = row0 + r0, rb = ra + 1;
    if (ra < n) {
        float d0 = dinv[ra];
        float4* Hv = (float4*)(H + (size_t)ra * F);
        float4 o0 = {a00.x * d0, a00.y * d0, a00.z * d0, a00.w * d0};
        float4 o1 = {a01.x * d0, a01.y * d0, a01.z * d0, a01.w * d0};
        Hv[c * 2] = o0; Hv[c * 2 + 1] = o1;
    }
    if (rb < n) {
        float d1 = dinv[rb];
        float4* Hv = (float4*)(H + (size_t)rb * F);
        float4 o0 = {a10.x * d1, a10.y * d1, a10.z * d1, a10.w * d1};
        float4 o1 = {a11.x * d1, a11.y * d1, a11.z * d1, a11.w * d1};
        Hv[c * 2] = o0; Hv[c * 2 + 1] = o1;
    }
}

// ---------- gather-aggregate + epilogue ----------
// FQ float4-chunks per row; FQ threads per node; unroll-4 over edges for MLP.
template <int FQ, int NPB, bool RELU>
__global__ __launch_bounds__(FQ * NPB) void agg_kernel(const float4* __restrict__ H,
                                                       const int* __restrict__ row_ptr,
                                                       const int* __restrict__ esrc,
                                                       const float* __restrict__ dinv,
                                                       const float4* __restrict__ b,
                                                       float4* __restrict__ out, int n) {
    const int tid = threadIdx.x;
    const int node = blockIdx.x * NPB + tid / FQ;
    const int q = tid % FQ;
    if (node >= n) return;
    float4 acc = H[(size_t)node * FQ + q];  // self loop
    const int beg = row_ptr[node], end = row_ptr[node + 1];
    int e = beg;
    for (; e + 4 <= end; e += 4) {
        int s0 = esrc[e + 0], s1 = esrc[e + 1], s2 = esrc[e + 2], s3 = esrc[e + 3];
        float4 v0 = H[(size_t)s0 * FQ + q];
        float4 v1 = H[(size_t)s1 * FQ + q];
        float4 v2 = H[(size_t)s2 * FQ + q];
        float4 v3 = H[(size_t)s3 * FQ + q];
        acc.x += (v0.x + v1.x) + (v2.x + v3.x);
        acc.y += (v0.y + v1.y) + (v2.y + v3.y);
        acc.z += (v0.z + v1.z) + (v2.z + v3.z);
        acc.w += (v0.w + v1.w) + (v2.w + v3.w);
    }
    for (; e < end; ++e) {
        int s = esrc[e];
        float4 v = H[(size_t)s * FQ + q];
        acc.x += v.x; acc.y += v.y; acc.z += v.z; acc.w += v.w;
    }
    float di = dinv[node];
    float4 bb = b[q];
    float4 r;
    r.x = acc.x * di + bb.x;
    r.y = acc.y * di + bb.y;
    r.z = acc.z * di + bb.z;
    r.w = acc.w * di + bb.w;
    if (RELU) {
        r.x = fmaxf(r.x, 0.0f); r.y = fmaxf(r.y, 0.0f);
        r.z = fmaxf(r.z, 0.0f); r.w = fmaxf(r.w, 0.0f);
    }
    out[(size_t)node * FQ + q] = r;
}

extern "C" void kernel_launch(void* const* d_in, const int* in_sizes, int n_in,
                              void* d_out, int out_size, void* d_ws, size_t ws_size,
                              hipStream_t stream) {
    const float* x   = (const float*)d_in[0];
    const int*  eidx = (const int*)d_in[1];
    const float* W1  = (const float*)d_in[2];
    const float* b1  = (const float*)d_in[3];
    const float* W2  = (const float*)d_in[4];
    const float* b2  = (const float*)d_in[5];

    const int IN = 96, HID = 96, OUT = 32;
    const int N = in_sizes[0] / IN;   // 50000
    const int E = in_sizes[1] / 2;    // 800000
    const int* src = eidx;
    const int* dst = eidx + E;

    float* out  = (float*)d_out;
    float* x1   = out;                       // [N, 96]
    float* out2 = out + (size_t)N * HID;     // [N, 32]

    auto align512 = [](size_t v) { return ((v + 511) / 512) * 512; };
    char* ws = (char*)d_ws;
    size_t off = 0;
    float* dinv   = (float*)(ws + off); off += align512((size_t)N * 4);
    int* deg      = (int*)(ws + off);   off += align512((size_t)N * 4);   // reused as cursor
    int* row_ptr  = (int*)(ws + off);   off += align512((size_t)(N + 1) * 4);
    int* bsum     = (int*)(ws + off);   off += align512(64 * 4);
    int* esrc     = (int*)(ws + off);   off += align512((size_t)E * 4);
    float* hp     = (float*)(ws + off); off += align512((size_t)N * 96 * 4);

    const int nb = (N + 1023) / 1024;

    // ---- CSR build (once, reused by both layers) ----
    hipMemsetAsync(deg, 0, (size_t)N * sizeof(int), stream);
    deg_int_kernel<<<(E + 255) / 256, 256, 0, stream>>>(dst, deg, E);
    dinv_kernel<<<(N + 255) / 256, 256, 0, stream>>>(deg, dinv, N);
    scan1<<<nb, 256, 0, stream>>>(deg, row_ptr + 1, bsum, N);
    scan2<<<1, 64, 0, stream>>>(bsum, nb);
    scan3<<<(N + 255) / 256, 256, 0, stream>>>(row_ptr, bsum, N);
    hipMemsetAsync(deg, 0, (size_t)N * sizeof(int), stream);  // reuse as cursor
    fill_kernel<<<(E + 255) / 256, 256, 0, stream>>>(src, dst, row_ptr, deg, esrc, E);

    // ---- Layer 1 ----
    gemm_tile<96, 32, 192><<<(N + 31) / 32, 192, 0, stream>>>(x, W1, dinv, hp, N);
    agg_kernel<24, 8, true><<<(N + 7) / 8, 192, 0, stream>>>(
        (const float4*)hp, row_ptr, esrc, dinv, (const float4*)b1, (float4*)x1, N);

    // ---- Layer 2 ----
    gemm_tile<32, 64, 128><<<(N + 63) / 64, 128, 0, stream>>>(x1, W2, dinv, hp, N);
    agg_kernel<8, 32, false><<<(N + 31) / 32, 256, 0, stream>>>(
        (const float4*)hp, row_ptr, esrc, dinv, (const float4*)b2, (float4*)out2, N);
}

// Round 5
// 162.782 us; speedup vs baseline: 9.0831x; 1.2585x over previous
//
#include <hip/hip_runtime.h>

// GCN 2-layer forward, f32 — gather formulation with binned-counting-sort CSR build.
// Requires N <= 65536 (src/dst packed into 16 bits each). Here N=50000, E=800000.
//
// h' = (x @ W) * dinv[row]
// out[i] = act( dinv[i] * ( sum_{e: dst=i} h'[src_e] + h'[i] ) + b )

#define MAXBINS 256  // supports N <= 65536 (bin = dst>>8)

// ---------- pass A: LDS-staged multisplit of edges into coarse bins ----------
// Packed entry p = ((dst&255)<<16) | src. Global bucket writes are flushed in
// multiples of 16 entries (64B) so every line is fully written once (no write amp).
template <int NT, int BINCAP>
__global__ __launch_bounds__(NT) void binA_kernel(const int* __restrict__ src,
                                                  const int* __restrict__ dst,
                                                  int* __restrict__ gcur,
                                                  unsigned* __restrict__ gbin,
                                                  int nbins, int capg, int E, int chunk) {
    __shared__ int scur[MAXBINS];
    __shared__ unsigned sbuf[MAXBINS * BINCAP];
    const int tid = threadIdx.x;
    const int beg = blockIdx.x * chunk;
    const int end = min(beg + chunk, E);
    for (int i = tid; i < MAXBINS; i += NT) scur[i] = 0;
    __syncthreads();
    for (int base = beg; base < end; base += NT) {
        int e = base + tid;
        if (e < end) {
            int s = src[e], d = dst[e];
            int bin = d >> 8;
            unsigned p = ((unsigned)(d & 255) << 16) | (unsigned)s;
            int slot = atomicAdd(&scur[bin], 1);
            if (slot < BINCAP) {
                sbuf[bin * BINCAP + slot] = p;
            } else {  // vanishingly rare for uniform dst; perf-only penalty
                atomicSub(&scur[bin], 1);
                int gp = atomicAdd(&gcur[bin], 1);
                gbin[(size_t)bin * capg + gp] = p;
            }
        }
        __syncthreads();
        if (tid < nbins) {
            int cnt = scur[tid];
            int nf = cnt & ~15;  // flush whole 64B groups only
            if (nf > 0) {
                int gp = atomicAdd(&gcur[tid], nf);
                const int4* s4 = (const int4*)&sbuf[tid * BINCAP];
                int4* d4 = (int4*)&gbin[(size_t)tid * capg + gp];
                for (int i = 0; i < nf / 4; ++i) d4[i] = s4[i];
                for (int i = 0; i < cnt - nf; ++i)
                    sbuf[tid * BINCAP + i] = sbuf[tid * BINCAP + nf + i];
                scur[tid] = cnt - nf;
            }
        }
        __syncthreads();
    }
    if (tid < nbins) {  // tail flush (partial lines, once per block per bin)
        int cnt = scur[tid];
        if (cnt > 0) {
            int gp = atomicAdd(&gcur[tid], cnt);
            for (int i = 0; i < cnt; ++i)
                gbin[(size_t)tid * capg + gp + i] = sbuf[tid * BINCAP + i];
        }
    }
}

// ---------- pass A2: scan bin counts ----------
__global__ __launch_bounds__(256) void binscan_kernel(const int* __restrict__ gcur,
                                                      int* __restrict__ binbase,
                                                      int* __restrict__ row_ptr,
                                                      int nbins, int n, int E) {
    __shared__ int s[256];
    const int tid = threadIdx.x;
    int v = (tid < nbins) ? gcur[tid] : 0;
    s[tid] = v;
    __syncthreads();
    for (int off = 1; off < 256; off <<= 1) {
        int t = (tid >= off) ? s[tid - off] : 0;
        __syncthreads();
        s[tid] += t;
        __syncthreads();
    }
    if (tid < nbins) binbase[tid] = s[tid] - v;
    if (tid == 0) row_ptr[n] = E;
}

// ---------- pass B: per-bin histogram (=degree) + scan (=row_ptr) + scatter ----------
__global__ __launch_bounds__(256) void binB_kernel(const unsigned* __restrict__ gbin,
                                                   const int* __restrict__ gcur,
                                                   const int* __restrict__ binbase,
                                                   int capg,
                                                   float* __restrict__ dinv,
                                                   int* __restrict__ row_ptr,
                                                   int* __restrict__ esrc, int n) {
    __shared__ int hist[256];
    __shared__ int scan[256];
    __shared__ int lbase[256];
    const int tid = threadIdx.x;
    const int bin = blockIdx.x;
    const int cnt = gcur[bin];
    const int base = binbase[bin];
    const unsigned* ebin = gbin + (size_t)bin * capg;
    hist[tid] = 0;
    __syncthreads();
    for (int i = tid; i < cnt; i += 256) atomicAdd(&hist[ebin[i] >> 16], 1);
    __syncthreads();
    int v = hist[tid];
    scan[tid] = v;
    __syncthreads();
    for (int off = 1; off < 256; off <<= 1) {
        int t = (tid >= off) ? scan[tid - off] : 0;
        __syncthreads();
        scan[tid] += t;
        __syncthreads();
    }
    lbase[tid] = scan[tid] - v;  // exclusive prefix within bin
    const int node = bin * 256 + tid;
    if (node < n) {
        dinv[node] = rsqrtf((float)v + 1.0f);  // +1 = self loop
        row_ptr[node] = base + lbase[tid];
    }
    hist[tid] = 0;  // reuse as per-node cursor
    __syncthreads();
    for (int i = tid; i < cnt; i += 256) {
        unsigned p = ebin[i];
        int local = p >> 16;
        int pos = base + lbase[local] + atomicAdd(&hist[local], 1);
        esrc[pos] = (int)(p & 0xFFFFu);  // writes land in this bin's contiguous region
    }
}

// ---------- GEMM: H[row,f] = dinv[row] * sum_k X[row,k] * W[k,f] ----------
template <int F, int ROWS, int NT>
__global__ __launch_bounds__(NT) void gemm_tile(const float* __restrict__ X,
                                                const float* __restrict__ W,
                                                const float* __restrict__ dinv,
                                                float* __restrict__ H, int n) {
    constexpr int K = 96;
    constexpr int CQ2 = F / 8;
    __shared__ float sX[ROWS * K];
    __shared__ float sW[K * F];
    const int tid = threadIdx.x;
    const int row0 = blockIdx.x * ROWS;
    {
        const float4* Wv = (const float4*)W;
        float4* sWv = (float4*)sW;
        for (int i = tid; i < K * F / 4; i += NT) sWv[i] = Wv[i];
    }
    if (row0 + ROWS <= n) {
        const float4* Xv = (const float4*)(X + (size_t)row0 * K);
        float4* sXv = (float4*)sX;
        for (int i = tid; i < ROWS * K / 4; i += NT) sXv[i] = Xv[i];
    } else {
        for (int i = tid; i < ROWS * K; i += NT) {
            int r = row0 + i / K;
            sX[i] = (r < n) ? X[(size_t)r * K + (i % K)] : 0.0f;
        }
    }
    __syncthreads();
    const int rp = tid / CQ2;
    const int c = tid % CQ2;
    const int r0 = rp * 2;
    float4 a00 = {0, 0, 0, 0}, a01 = {0, 0, 0, 0};
    float4 a10 = {0, 0, 0, 0}, a11 = {0, 0, 0, 0};
    const float4* sWv = (const float4*)sW;
#pragma unroll 4
    for (int k = 0; k < K; ++k) {
        float x0 = sX[r0 * K + k];
        float x1 = sX[(r0 + 1) * K + k];
        float4 w0 = sWv[k * (F / 4) + c * 2];
        float4 w1 = sWv[k * (F / 4) + c * 2 + 1];
        a00.x += x0 * w0.x; a00.y += x0 * w0.y; a00.z += x0 * w0.z; a00.w += x0 * w0.w;
        a01.x += x0 * w1.x; a01.y += x0 * w1.y; a01.z += x0 * w1.z; a01.w += x0 * w1.w;
        a10.x += x1 * w0.x; a10.y += x1 * w0.y; a10.z += x1 * w0.z; a10.w += x1 * w0.w;
        a11.x += x1 * w1.x; a11.y += x1 * w1.y; a11.z += x1 * w1.z; a11.w += x1 * w1.w;
    }
    int ra = row0 + r0, rb = ra + 1;
    if (ra < n) {
        float d0 = dinv[ra];
        float4* Hv = (float4*)(H + (size_t)ra * F);
        float4 o0 = {a00.x * d0, a00.y * d0, a00.z * d0, a00.w * d0};
        float4 o1 = {a01.x * d0, a01.y * d0, a01.z * d0, a01.w * d0};
        Hv[c * 2] = o0; Hv[c * 2 + 1] = o1;
    }
    if (rb < n) {
        float d1 = dinv[rb];
        float4* Hv = (float4*)(H + (size_t)rb * F);
        float4 o0 = {a10.x * d1, a10.y * d1, a10.z * d1, a10.w * d1};
        float4 o1 = {a11.x * d1, a11.y * d1, a11.z * d1, a11.w * d1};
        Hv[c * 2] = o0; Hv[c * 2 + 1] = o1;
    }
}

// ---------- gather-aggregate + epilogue ----------
template <int FQ, int NPB, bool RELU>
__global__ __launch_bounds__(FQ * NPB) void agg_kernel(const float4* __restrict__ H,
                                                       const int* __restrict__ row_ptr,
                                                       const int* __restrict__ esrc,
                                                       const float* __restrict__ dinv,
                                                       const float4* __restrict__ b,
                                                       float4* __restrict__ out, int n) {
    const int tid = threadIdx.x;
    const int node = blockIdx.x * NPB + tid / FQ;
    const int q = tid % FQ;
    if (node >= n) return;
    float4 acc = H[(size_t)node * FQ + q];  // self loop
    const int beg = row_ptr[node], end = row_ptr[node + 1];
    int e = beg;
    for (; e + 4 <= end; e += 4) {
        int s0 = esrc[e + 0], s1 = esrc[e + 1], s2 = esrc[e + 2], s3 = esrc[e + 3];
        float4 v0 = H[(size_t)s0 * FQ + q];
        float4 v1 = H[(size_t)s1 * FQ + q];
        float4 v2 = H[(size_t)s2 * FQ + q];
        float4 v3 = H[(size_t)s3 * FQ + q];
        acc.x += (v0.x + v1.x) + (v2.x + v3.x);
        acc.y += (v0.y + v1.y) + (v2.y + v3.y);
        acc.z += (v0.z + v1.z) + (v2.z + v3.z);
        acc.w += (v0.w + v1.w) + (v2.w + v3.w);
    }
    for (; e < end; ++e) {
        int s = esrc[e];
        float4 v = H[(size_t)s * FQ + q];
        acc.x += v.x; acc.y += v.y; acc.z += v.z; acc.w += v.w;
    }
    float di = dinv[node];
    float4 bb = b[q];
    float4 r;
    r.x = acc.x * di + bb.x;
    r.y = acc.y * di + bb.y;
    r.z = acc.z * di + bb.z;
    r.w = acc.w * di + bb.w;
    if (RELU) {
        r.x = fmaxf(r.x, 0.0f); r.y = fmaxf(r.y, 0.0f);
        r.z = fmaxf(r.z, 0.0f); r.w = fmaxf(r.w, 0.0f);
    }
    out[(size_t)node * FQ + q] = r;
}

extern "C" void kernel_launch(void* const* d_in, const int* in_sizes, int n_in,
                              void* d_out, int out_size, void* d_ws, size_t ws_size,
                              hipStream_t stream) {
    const float* x   = (const float*)d_in[0];
    const int*  eidx = (const int*)d_in[1];
    const float* W1  = (const float*)d_in[2];
    const float* b1  = (const float*)d_in[3];
    const float* W2  = (const float*)d_in[4];
    const float* b2  = (const float*)d_in[5];

    const int IN = 96, HID = 96, OUT = 32;
    const int N = in_sizes[0] / IN;   // 50000 (must be <= 65536 for 16-bit packing)
    const int E = in_sizes[1] / 2;    // 800000
    const int* src = eidx;
    const int* dst = eidx + E;

    float* out  = (float*)d_out;
    float* x1   = out;                       // [N, 96]
    float* out2 = out + (size_t)N * HID;     // [N, 32]

    const int nbins = (N + 255) / 256;       // 196
    const int capg = 8192;                   // per-bin capacity (avg 4082, uniform dst)

    auto align512 = [](size_t v) { return ((v + 511) / 512) * 512; };
    char* ws = (char*)d_ws;
    size_t off = 0;
    float* dinv    = (float*)(ws + off); off += align512((size_t)N * 4);
    int* row_ptr   = (int*)(ws + off);   off += align512((size_t)(N + 1) * 4);
    int* esrc      = (int*)(ws + off);   off += align512((size_t)E * 4);
    int* gcur      = (int*)(ws + off);   off += align512(MAXBINS * 4);
    int* binbase   = (int*)(ws + off);   off += align512(MAXBINS * 4);
    // gbin overlaid on hp: lifetimes disjoint (gbin: binA..binB; hp: gemm..agg)
    char* big      = ws + off;           // max(nbins*capg*4 = 6.4MB, N*96*4 = 19.2MB)
    unsigned* gbin = (unsigned*)big;
    float* hp      = (float*)big;

    // ---- CSR build ----
    hipMemsetAsync(gcur, 0, MAXBINS * sizeof(int), stream);
    {
        const int nblk = 192;
        const int chunk = (E + nblk - 1) / nblk;
        binA_kernel<256, 32><<<nblk, 256, 0, stream>>>(src, dst, gcur, gbin,
                                                       nbins, capg, E, chunk);
    }
    binscan_kernel<<<1, 256, 0, stream>>>(gcur, binbase, row_ptr, nbins, N, E);
    binB_kernel<<<nbins, 256, 0, stream>>>(gbin, gcur, binbase, capg,
                                           dinv, row_ptr, esrc, N);

    // ---- Layer 1 ----
    gemm_tile<96, 32, 192><<<(N + 31) / 32, 192, 0, stream>>>(x, W1, dinv, hp, N);
    agg_kernel<24, 8, true><<<(N + 7) / 8, 192, 0, stream>>>(
        (const float4*)hp, row_ptr, esrc, dinv, (const float4*)b1, (float4*)x1, N);

    // ---- Layer 2 ----
    gemm_tile<32, 64, 128><<<(N + 63) / 64, 128, 0, stream>>>(x1, W2, dinv, hp, N);
    agg_kernel<8, 32, false><<<(N + 31) / 32, 256, 0, stream>>>(
        (const float4*)hp, row_ptr, esrc, dinv, (const float4*)b2, (float4*)out2, N);
}

// Round 6
// 115.107 us; speedup vs baseline: 12.8452x; 1.4142x over previous
//
#include <hip/hip_runtime.h>

// GCN 2-layer forward — gather formulation, bf16 gather table, atomic-free
// fully-parallel CSR build (local counting sort per chunk + per-bin merge).
// Requires N <= 65536 (16-bit packing). Here N=50000, E=800000.
//
// h' = bf16( (x @ W) * dinv[row] )
// out[i] = act( dinv[i] * ( sum_{e: dst=i} h'[src_e] + h'[i] ) + b )

#define NBINS_CAP 256   // bin = dst>>8  (N <= 65536)
#define MAXBLK 512      // max binA chunks (E <= 512*2048)
#define CHUNK 2048      // edges per binA block

__device__ __forceinline__ unsigned short f2bf(float f) {
    unsigned u = __float_as_uint(f);
    u = u + 0x7FFFu + ((u >> 16) & 1u);  // round-to-nearest-even
    return (unsigned short)(u >> 16);
}
__device__ __forceinline__ float bflo(unsigned w) { return __uint_as_float(w << 16); }
__device__ __forceinline__ float bfhi(unsigned w) { return __uint_as_float(w & 0xFFFF0000u); }

// ---------- binA: per-chunk LDS counting sort; coalesced slab write ----------
template <int NT>
__global__ __launch_bounds__(NT) void binA_kernel(const int* __restrict__ src,
                                                  const int* __restrict__ dst,
                                                  unsigned* __restrict__ slab,
                                                  int* __restrict__ cnt,
                                                  int* __restrict__ seg,
                                                  int nbins, int E) {
    constexpr int PT = CHUNK / NT;
    __shared__ unsigned ebuf[CHUNK];
    __shared__ int hist[NBINS_CAP];
    __shared__ int cur[NBINS_CAP];
    __shared__ int sc[NT];
    const int tid = threadIdx.x;
    const int beg = blockIdx.x * CHUNK;
    const int cntE = min(CHUNK, E - beg);
    for (int i = tid; i < nbins; i += NT) hist[i] = 0;
    __syncthreads();
    unsigned pv[PT];
    int pb[PT];
#pragma unroll
    for (int j = 0; j < PT; ++j) {
        int idx = j * NT + tid;
        if (idx < cntE) {
            int e = beg + idx;
            int s = src[e], d = dst[e];
            pb[j] = d >> 8;
            pv[j] = ((unsigned)(d & 255) << 16) | (unsigned)s;
            atomicAdd(&hist[pb[j]], 1);
        } else {
            pb[j] = -1;
        }
    }
    __syncthreads();
    int v = (tid < nbins) ? hist[tid] : 0;
    sc[tid] = v;
    __syncthreads();
    for (int off = 1; off < NT; off <<= 1) {
        int t = (tid >= off) ? sc[tid - off] : 0;
        __syncthreads();
        sc[tid] += t;
        __syncthreads();
    }
    if (tid < nbins) cur[tid] = sc[tid] - v;  // exclusive offset; advances as cursor
    __syncthreads();
#pragma unroll
    for (int j = 0; j < PT; ++j) {
        if (pb[j] >= 0) {
            int pos = atomicAdd(&cur[pb[j]], 1);
            ebuf[pos] = pv[j];
        }
    }
    __syncthreads();
    for (int i = tid; i < cntE; i += NT) slab[beg + i] = ebuf[i];  // coalesced
    for (int i = tid; i < nbins; i += NT) {
        cnt[blockIdx.x * nbins + i] = hist[i];
        seg[blockIdx.x * nbins + i] = cur[i] - hist[i];  // segment start in chunk
    }
}

// ---------- binsum: per-bin total over chunks ----------
__global__ __launch_bounds__(256) void binsum_kernel(const int* __restrict__ cnt,
                                                     int* __restrict__ btotal,
                                                     int nbins, int nblk) {
    __shared__ int r[256];
    const int bin = blockIdx.x, tid = threadIdx.x;
    int s = 0;
    for (int b = tid; b < nblk; b += 256) s += cnt[b * nbins + bin];
    r[tid] = s;
    __syncthreads();
    for (int off = 128; off; off >>= 1) {
        if (tid < off) r[tid] += r[tid + off];
        __syncthreads();
    }
    if (tid == 0) btotal[bin] = r[0];
}

// ---------- binscan: exclusive scan of bin totals ----------
__global__ __launch_bounds__(256) void binscan_kernel(const int* __restrict__ btotal,
                                                      int* __restrict__ binbase,
                                                      int* __restrict__ row_ptr,
                                                      int nbins, int n, int E) {
    __shared__ int s[256];
    const int tid = threadIdx.x;
    int v = (tid < nbins) ? btotal[tid] : 0;
    s[tid] = v;
    __syncthreads();
    for (int off = 1; off < 256; off <<= 1) {
        int t = (tid >= off) ? s[tid - off] : 0;
        __syncthreads();
        s[tid] += t;
        __syncthreads();
    }
    if (tid < nbins) binbase[tid] = s[tid] - v;
    if (tid == 0) row_ptr[n] = E;
}

// ---------- binB: per-bin merge — degree/dinv/row_ptr + contiguous esrc ----------
__global__ __launch_bounds__(256) void binB_kernel(const unsigned* __restrict__ slab,
                                                   const int* __restrict__ cnt,
                                                   const int* __restrict__ seg,
                                                   const int* __restrict__ binbase,
                                                   float* __restrict__ dinv,
                                                   int* __restrict__ row_ptr,
                                                   int* __restrict__ esrc,
                                                   int n, int nbins, int nblk) {
    constexpr int NT = 256;
    __shared__ int segc[MAXBLK], segs[MAXBLK];
    __shared__ int sc[NT];
    __shared__ int hist[256], lbase[256], cur[256];
    const int tid = threadIdx.x;
    const int bin = blockIdx.x;
    for (int b = tid; b < MAXBLK; b += NT) {
        segc[b] = (b < nblk) ? cnt[b * nbins + bin] : 0;
        segs[b] = (b < nblk) ? seg[b * nbins + bin] : 0;
    }
    hist[tid] = 0;
    __syncthreads();
    // histogram of local node ids within this bin
    for (int b = tid; b < nblk; b += NT) {
        int c = segc[b];
        const unsigned* p = slab + (size_t)b * CHUNK + segs[b];
        for (int i = 0; i < c; ++i) atomicAdd(&hist[p[i] >> 16], 1);
    }
    __syncthreads();
    int v = hist[tid];
    sc[tid] = v;
    __syncthreads();
    for (int off = 1; off < NT; off <<= 1) {
        int t = (tid >= off) ? sc[tid - off] : 0;
        __syncthreads();
        sc[tid] += t;
        __syncthreads();
    }
    lbase[tid] = sc[tid] - v;
    cur[tid] = 0;
    const int base = binbase[bin];
    const int node = bin * 256 + tid;
    if (node < n) {
        dinv[node] = rsqrtf((float)v + 1.0f);  // +1 = self loop
        row_ptr[node] = base + lbase[tid];
    }
    __syncthreads();
    // scatter src ids into this bin's contiguous region (block-owned lines)
    for (int b = tid; b < nblk; b += NT) {
        int c = segc[b];
        const unsigned* p = slab + (size_t)b * CHUNK + segs[b];
        for (int i = 0; i < c; ++i) {
            unsigned e = p[i];
            int local = e >> 16;
            int pos = base + lbase[local] + atomicAdd(&cur[local], 1);
            esrc[pos] = (int)(e & 0xFFFFu);
        }
    }
}

// ---------- GEMM: Hb[row,f] = bf16( dinv[row] * sum_k X[row,k] * W[k,f] ) ----------
template <int F, int ROWS, int NT>
__global__ __launch_bounds__(NT) void gemm_tile(const float* __restrict__ X,
                                                const float* __restrict__ W,
                                                const float* __restrict__ dinv,
                                                unsigned short* __restrict__ Hb, int n) {
    constexpr int K = 96;
    constexpr int CQ2 = F / 8;
    __shared__ float sX[ROWS * K];
    __shared__ float sW[K * F];
    const int tid = threadIdx.x;
    const int row0 = blockIdx.x * ROWS;
    {
        const float4* Wv = (const float4*)W;
        float4* sWv = (float4*)sW;
        for (int i = tid; i < K * F / 4; i += NT) sWv[i] = Wv[i];
    }
    if (row0 + ROWS <= n) {
        const float4* Xv = (const float4*)(X + (size_t)row0 * K);
        float4* sXv = (float4*)sX;
        for (int i = tid; i < ROWS * K / 4; i += NT) sXv[i] = Xv[i];
    } else {
        for (int i = tid; i < ROWS * K; i += NT) {
            int r = row0 + i / K;
            sX[i] = (r < n) ? X[(size_t)r * K + (i % K)] : 0.0f;
        }
    }
    __syncthreads();
    const int rp = tid / CQ2;
    const int c = tid % CQ2;
    const int r0 = rp * 2;
    float4 a00 = {0, 0, 0, 0}, a01 = {0, 0, 0, 0};
    float4 a10 = {0, 0, 0, 0}, a11 = {0, 0, 0, 0};
    const float4* sWv = (const float4*)sW;
#pragma unroll 4
    for (int k = 0; k < K; ++k) {
        float x0 = sX[r0 * K + k];
        float x1 = sX[(r0 + 1) * K + k];
        float4 w0 = sWv[k * (F / 4) + c * 2];
        float4 w1 = sWv[k * (F / 4) + c * 2 + 1];
        a00.x += x0 * w0.x; a00.y += x0 * w0.y; a00.z += x0 * w0.z; a00.w += x0 * w0.w;
        a01.x += x0 * w1.x; a01.y += x0 * w1.y; a01.z += x0 * w1.z; a01.w += x0 * w1.w;
        a10.x += x1 * w0.x; a10.y += x1 * w0.y; a10.z += x1 * w0.z; a10.w += x1 * w0.w;
        a11.x += x1 * w1.x; a11.y += x1 * w1.y; a11.z += x1 * w1.z; a11.w += x1 * w1.w;
    }
    int ra = row0 + r0, rb = ra + 1;
    if (ra < n) {
        float d0 = dinv[ra];
        uint4 w;
        w.x = (unsigned)f2bf(a00.x * d0) | ((unsigned)f2bf(a00.y * d0) << 16);
        w.y = (unsigned)f2bf(a00.z * d0) | ((unsigned)f2bf(a00.w * d0) << 16);
        w.z = (unsigned)f2bf(a01.x * d0) | ((unsigned)f2bf(a01.y * d0) << 16);
        w.w = (unsigned)f2bf(a01.z * d0) | ((unsigned)f2bf(a01.w * d0) << 16);
        ((uint4*)(Hb + (size_t)ra * F))[c] = w;
    }
    if (rb < n) {
        float d1 = dinv[rb];
        uint4 w;
        w.x = (unsigned)f2bf(a10.x * d1) | ((unsigned)f2bf(a10.y * d1) << 16);
        w.y = (unsigned)f2bf(a10.z * d1) | ((unsigned)f2bf(a10.w * d1) << 16);
        w.z = (unsigned)f2bf(a11.x * d1) | ((unsigned)f2bf(a11.y * d1) << 16);
        w.w = (unsigned)f2bf(a11.z * d1) | ((unsigned)f2bf(a11.w * d1) << 16);
        ((uint4*)(Hb + (size_t)rb * F))[c] = w;
    }
}

// ---------- gather-aggregate + epilogue (bf16 table, f32 accum) ----------
// FC = uint4 chunks per row (8 bf16 each); FC threads per node.
#define ACC8(vv)                                                        \
    do {                                                                \
        acc0 += bflo(vv.x); acc1 += bfhi(vv.x);                         \
        acc2 += bflo(vv.y); acc3 += bfhi(vv.y);                         \
        acc4 += bflo(vv.z); acc5 += bfhi(vv.z);                         \
        acc6 += bflo(vv.w); acc7 += bfhi(vv.w);                         \
    } while (0)

template <int FC, int NPB, bool RELU, int NT>
__global__ __launch_bounds__(NT) void agg_kernel(const uint4* __restrict__ H,
                                                 const int* __restrict__ row_ptr,
                                                 const int* __restrict__ esrc,
                                                 const float* __restrict__ dinv,
                                                 const float* __restrict__ b,
                                                 float* __restrict__ out, int n) {
    constexpr int F = FC * 8;
    const int tid = threadIdx.x;
    const int node = blockIdx.x * NPB + tid / FC;
    const int q = tid % FC;
    if (node >= n) return;
    float acc0 = 0, acc1 = 0, acc2 = 0, acc3 = 0, acc4 = 0, acc5 = 0, acc6 = 0, acc7 = 0;
    {
        uint4 v = H[(size_t)node * FC + q];  // self loop
        ACC8(v);
    }
    const int beg = row_ptr[node], end = row_ptr[node + 1];
    int e = beg;
    for (; e + 4 <= end; e += 4) {
        int s0 = esrc[e + 0], s1 = esrc[e + 1], s2 = esrc[e + 2], s3 = esrc[e + 3];
        uint4 v0 = H[(size_t)s0 * FC + q];
        uint4 v1 = H[(size_t)s1 * FC + q];
        uint4 v2 = H[(size_t)s2 * FC + q];
        uint4 v3 = H[(size_t)s3 * FC + q];
        ACC8(v0); ACC8(v1); ACC8(v2); ACC8(v3);
    }
    for (; e < end; ++e) {
        uint4 v = H[(size_t)esrc[e] * FC + q];
        ACC8(v);
    }
    const float di = dinv[node];
    const int f0 = q * 8;
    float4 o0, o1;
    o0.x = acc0 * di + b[f0 + 0];
    o0.y = acc1 * di + b[f0 + 1];
    o0.z = acc2 * di + b[f0 + 2];
    o0.w = acc3 * di + b[f0 + 3];
    o1.x = acc4 * di + b[f0 + 4];
    o1.y = acc5 * di + b[f0 + 5];
    o1.z = acc6 * di + b[f0 + 6];
    o1.w = acc7 * di + b[f0 + 7];
    if (RELU) {
        o0.x = fmaxf(o0.x, 0.0f); o0.y = fmaxf(o0.y, 0.0f);
        o0.z = fmaxf(o0.z, 0.0f); o0.w = fmaxf(o0.w, 0.0f);
        o1.x = fmaxf(o1.x, 0.0f); o1.y = fmaxf(o1.y, 0.0f);
        o1.z = fmaxf(o1.z, 0.0f); o1.w = fmaxf(o1.w, 0.0f);
    }
    float4* op = (float4*)(out + (size_t)node * F);
    op[q * 2 + 0] = o0;
    op[q * 2 + 1] = o1;
}

extern "C" void kernel_launch(void* const* d_in, const int* in_sizes, int n_in,
                              void* d_out, int out_size, void* d_ws, size_t ws_size,
                              hipStream_t stream) {
    const float* x   = (const float*)d_in[0];
    const int*  eidx = (const int*)d_in[1];
    const float* W1  = (const float*)d_in[2];
    const float* b1  = (const float*)d_in[3];
    const float* W2  = (const float*)d_in[4];
    const float* b2  = (const float*)d_in[5];

    const int IN = 96, HID = 96, OUT = 32;
    const int N = in_sizes[0] / IN;   // 50000 (<= 65536 for 16-bit packing)
    const int E = in_sizes[1] / 2;    // 800000
    const int* src = eidx;
    const int* dst = eidx + E;

    float* out  = (float*)d_out;
    float* x1   = out;                       // [N, 96] f32
    float* out2 = out + (size_t)N * HID;     // [N, 32] f32

    const int nbins = (N + 255) / 256;       // 196
    const int nblk = (E + CHUNK - 1) / CHUNK;  // 391 (<= MAXBLK)

    auto align512 = [](size_t v) { return ((v + 511) / 512) * 512; };
    char* ws = (char*)d_ws;
    size_t off = 0;
    float* dinv     = (float*)(ws + off); off += align512((size_t)N * 4);
    int* row_ptr    = (int*)(ws + off);   off += align512((size_t)(N + 1) * 4);
    int* esrc       = (int*)(ws + off);   off += align512((size_t)E * 4);
    unsigned* slab  = (unsigned*)(ws + off); off += align512((size_t)E * 4);
    int* cnt        = (int*)(ws + off);   off += align512((size_t)nblk * nbins * 4);
    int* seg        = (int*)(ws + off);   off += align512((size_t)nblk * nbins * 4);
    int* btotal     = (int*)(ws + off);   off += align512(NBINS_CAP * 4);
    int* binbase    = (int*)(ws + off);   off += align512(NBINS_CAP * 4);
    unsigned short* hb = (unsigned short*)(ws + off); off += align512((size_t)N * 96 * 2);

    // ---- CSR build (atomic-free, fully parallel) ----
    binA_kernel<256><<<nblk, 256, 0, stream>>>(src, dst, slab, cnt, seg, nbins, E);
    binsum_kernel<<<nbins, 256, 0, stream>>>(cnt, btotal, nbins, nblk);
    binscan_kernel<<<1, 256, 0, stream>>>(btotal, binbase, row_ptr, nbins, N, E);
    binB_kernel<<<nbins, 256, 0, stream>>>(slab, cnt, seg, binbase,
                                           dinv, row_ptr, esrc, N, nbins, nblk);

    // ---- Layer 1 ----
    gemm_tile<96, 32, 192><<<(N + 31) / 32, 192, 0, stream>>>(x, W1, dinv, hb, N);
    agg_kernel<12, 16, true, 192><<<(N + 15) / 16, 192, 0, stream>>>(
        (const uint4*)hb, row_ptr, esrc, dinv, b1, x1, N);

    // ---- Layer 2 ----
    gemm_tile<32, 64, 128><<<(N + 63) / 64, 128, 0, stream>>>(x1, W2, dinv, hb, N);
    agg_kernel<4, 64, false, 256><<<(N + 63) / 64, 256, 0, stream>>>(
        (const uint4*)hb, row_ptr, esrc, dinv, b2, out2, N);
}